// Round 2
// baseline (129.261 us; speedup 1.0000x reference)
//
#include <hip/hip_runtime.h>

#define N 8192
#define FIN 256
#define FOUT 64
#define ALPHA 0.2f

typedef float f32x4 __attribute__((ext_vector_type(4)));
typedef short s16x4 __attribute__((ext_vector_type(4)));

static __device__ __forceinline__ unsigned short f2bf(float x) {
    unsigned u = __float_as_uint(x);
    u += 0x7fffu + ((u >> 16) & 1u);
    return (unsigned short)(u >> 16);
}

// ---------------- Kernel 1: h = input@W + b_lin ---------------------------------------
// Writes hTf (bf16, 16x16 j-major tiles: element (f,j) at [(j>>4)*64+f]*16 + (j&15)),
// s1, s2, and atomicMax's the global s2 max (monotone-uint encoding).
// 512 blocks x 16 rows, 256 threads. Per-wave input staging (no block barrier needed).
__global__ __launch_bounds__(256) void k_linear(
    const float* __restrict__ input, const float* __restrict__ W,
    const float* __restrict__ b_lin, const float* __restrict__ a,
    unsigned short* __restrict__ hTf, float* __restrict__ s1, float* __restrict__ s2,
    unsigned* __restrict__ s2max_enc)
{
    __shared__ float in_sh[16 * FIN];     // 16 KB
    __shared__ float hst[64][17];         // transpose staging, stride 17 = conflict-free
    int t = threadIdx.x, w = t >> 6, f = t & 63;
    int i0 = blockIdx.x * 16;

    // wave w stages its own 4 rows (coalesced float4, same-wave RAW -> no barrier)
#pragma unroll
    for (int r = 0; r < 4; r++) {
        int row = w * 4 + r;
        *(float4*)&in_sh[row * FIN + f * 4] =
            *(const float4*)(input + (size_t)(i0 + row) * FIN + f * 4);
    }

    float a1v = a[f], a2v = a[FOUT + f];
    float h[4];
#pragma unroll
    for (int r = 0; r < 4; r++) h[r] = b_lin[f];

    for (int k4 = 0; k4 < FIN / 4; k4++) {
        float wv0 = W[(k4 * 4 + 0) * FOUT + f];
        float wv1 = W[(k4 * 4 + 1) * FOUT + f];
        float wv2 = W[(k4 * 4 + 2) * FOUT + f];
        float wv3 = W[(k4 * 4 + 3) * FOUT + f];
#pragma unroll
        for (int r = 0; r < 4; r++) {
            float4 iv = *(const float4*)&in_sh[(w * 4 + r) * FIN + k4 * 4];
            h[r] = fmaf(iv.x, wv0, h[r]);
            h[r] = fmaf(iv.y, wv1, h[r]);
            h[r] = fmaf(iv.z, wv2, h[r]);
            h[r] = fmaf(iv.w, wv3, h[r]);
        }
    }

    float wmax = -1e30f;
#pragma unroll
    for (int r = 0; r < 4; r++) {
        hst[f][w * 4 + r] = h[r];
        float v1 = h[r] * a1v, v2 = h[r] * a2v;
#pragma unroll
        for (int d = 1; d < 64; d <<= 1) { v1 += __shfl_xor(v1, d); v2 += __shfl_xor(v2, d); }
        wmax = fmaxf(wmax, v2);
        if (f == 0) { s1[i0 + w * 4 + r] = v1; s2[i0 + w * 4 + r] = v2; }
    }
    if (f == 0) {
        unsigned u = __float_as_uint(wmax);
        unsigned key = (u & 0x80000000u) ? ~u : (u | 0x80000000u);
        atomicMax(s2max_enc, key);
    }
    __syncthreads();

    // write hTf tile for this block (jb = blockIdx.x): fully coalesced 2 KB store
    int fo = t >> 2, seg = t & 3;
    unsigned lo = f2bf(hst[fo][seg * 4 + 0]) | ((unsigned)f2bf(hst[fo][seg * 4 + 1]) << 16);
    unsigned hi = f2bf(hst[fo][seg * 4 + 2]) | ((unsigned)f2bf(hst[fo][seg * 4 + 3]) << 16);
    int2 v; v.x = (int)lo; v.y = (int)hi;
    *(int2*)(hTf + ((size_t)blockIdx.x * 64 + fo) * 16 + seg * 4) = v;
}

// ---------------- Kernel 2: fused mask + exp + P@H via MFMA, barrier-free loop --------
// Grid: (N/64)*chunks blocks, 256 threads (4 waves x 16 rows). chunk = bid&7 = XCD id.
// B-fragments load straight from L2-resident hTf (512-B dense per fragment) -> no LDS
// tile, no per-iteration barriers; adj prefetched one iteration ahead.
__global__ __launch_bounds__(256) void k_attn(
    const int* __restrict__ adj, const float* __restrict__ s1g,
    const float* __restrict__ s2g, const unsigned short* __restrict__ hTf,
    const unsigned* __restrict__ s2max_enc, const float* __restrict__ bias,
    float* __restrict__ numP, float* __restrict__ denP, float* __restrict__ out,
    int log2c)
{
    extern __shared__ char smem[];
    int clen = N >> log2c;
    float* s2sh = (float*)smem;                       // clen floats
    float* densh = (float*)(smem + (clen << 2));      // 64 floats (direct path only)

    const float LOG2E = 1.4426950408889634f;
    int bid = blockIdx.x;
    int chunk = bid & ((1 << log2c) - 1);
    int rb = bid >> log2c;
    int jstart = chunk * clen;
    int t = threadIdx.x, w = t >> 6, l = t & 63;
    int l15 = l & 15, kg = l >> 4;
    int p_l = l15 * 16 + kg * 4;                      // lane offset inside a 16x16 hTf tile

    for (int idx = t; idx < (clen >> 2); idx += 256)
        ((float4*)s2sh)[idx] = ((const float4*)(s2g + jstart))[idx];

    int i0 = rb * 64;
    int i = i0 + w * 16 + l15;                        // this lane's P-row (A layout row)
    float s1v = s1g[i];
    unsigned key = *s2max_enc;
    unsigned su = (key & 0x80000000u) ? (key ^ 0x80000000u) : ~key;
    float s2m = __uint_as_float(su);
    float mx = s1v + s2m; mx = fmaxf(mx, ALPHA * mx); // leaky(s1+s2max) >= rowmax
    float m2 = mx * LOG2E;

    const int4* adjrow = (const int4*)(adj + (size_t)i * N);
    int jq = jstart >> 2;
    size_t jb0 = (size_t)(jstart >> 4);

    int4 acur[4];
#pragma unroll
    for (int kb = 0; kb < 4; kb++) acur[kb] = adjrow[jq + kb * 4 + kg];

    f32x4 acc[4] = {};
    float dacc = 0.f;
    __syncthreads();                                   // s2sh ready (only barrier)

    int iters = clen >> 6;
    for (int it = 0; it < iters; it++) {
        int4 anext[4];
        if (it + 1 < iters) {
#pragma unroll
            for (int kb = 0; kb < 4; kb++)
                anext[kb] = adjrow[jq + (it + 1) * 16 + kb * 4 + kg];
        }
        // A fragments (P values) in mfma_16x16x16 A layout: row=l15, k=kg*4+e
        s16x4 afr[4];
#pragma unroll
        for (int kb = 0; kb < 4; kb++) {
            float4 sv = *(const float4*)&s2sh[it * 64 + kb * 16 + kg * 4];
            int4 av = acur[kb];
            float p0, p1, p2, p3;
            { float x = s1v + sv.x; x = fmaxf(x, ALPHA * x); p0 = (av.x > 0) ? exp2f(fmaf(x, LOG2E, -m2)) : 0.f; }
            { float x = s1v + sv.y; x = fmaxf(x, ALPHA * x); p1 = (av.y > 0) ? exp2f(fmaf(x, LOG2E, -m2)) : 0.f; }
            { float x = s1v + sv.z; x = fmaxf(x, ALPHA * x); p2 = (av.z > 0) ? exp2f(fmaf(x, LOG2E, -m2)) : 0.f; }
            { float x = s1v + sv.w; x = fmaxf(x, ALPHA * x); p3 = (av.w > 0) ? exp2f(fmaf(x, LOG2E, -m2)) : 0.f; }
            dacc += (p0 + p1) + (p2 + p3);
            s16x4 af;
            af[0] = (short)f2bf(p0); af[1] = (short)f2bf(p1);
            af[2] = (short)f2bf(p2); af[3] = (short)f2bf(p3);
            afr[kb] = af;
        }
        // B fragments straight from L2-resident hTf; kb -> +1024 elems (next 16-j tile)
        const unsigned short* bp = hTf + (jb0 + (size_t)it * 4) * 1024 + p_l;
#pragma unroll
        for (int nt = 0; nt < 4; nt++) {
            const unsigned short* bq = bp + nt * 256;
            s16x4 b0 = *(const s16x4*)(bq);
            s16x4 b1 = *(const s16x4*)(bq + 1024);
            s16x4 b2 = *(const s16x4*)(bq + 2048);
            s16x4 b3 = *(const s16x4*)(bq + 3072);
            acc[nt] = __builtin_amdgcn_mfma_f32_16x16x16bf16_1k(afr[0], b0, acc[nt], 0, 0, 0);
            acc[nt] = __builtin_amdgcn_mfma_f32_16x16x16bf16_1k(afr[1], b1, acc[nt], 0, 0, 0);
            acc[nt] = __builtin_amdgcn_mfma_f32_16x16x16bf16_1k(afr[2], b2, acc[nt], 0, 0, 0);
            acc[nt] = __builtin_amdgcn_mfma_f32_16x16x16bf16_1k(afr[3], b3, acc[nt], 0, 0, 0);
        }
#pragma unroll
        for (int kb = 0; kb < 4; kb++) acur[kb] = anext[kb];
    }

    dacc += __shfl_xor(dacc, 16);
    dacc += __shfl_xor(dacc, 32);

    if (log2c == 0) {
        if (l < 16) densh[w * 16 + l] = dacc;
        __syncthreads();
#pragma unroll
        for (int nt = 0; nt < 4; nt++) {
#pragma unroll
            for (int r = 0; r < 4; r++) {
                int orow = w * 16 + kg * 4 + r;       // C layout: row=(l>>4)*4+r, col=l15
                out[(size_t)(i0 + orow) * FOUT + nt * 16 + l15] =
                    acc[nt][r] / densh[orow] + bias[nt * 16 + l15];
            }
        }
    } else {
        if (l < 16) denP[(size_t)chunk * N + i0 + w * 16 + l] = dacc;
#pragma unroll
        for (int nt = 0; nt < 4; nt++) {
#pragma unroll
            for (int r = 0; r < 4; r++) {
                int orow = w * 16 + kg * 4 + r;
                numP[((size_t)chunk * N + i0 + orow) * FOUT + nt * 16 + l15] = acc[nt][r];
            }
        }
    }
}

// ---------------- Kernel 3: combine chunk partials, divide, add bias ------------------
__global__ __launch_bounds__(256) void k_finalize(
    const float* __restrict__ numP, const float* __restrict__ denP,
    const float* __restrict__ bias, float* __restrict__ out, int chunks)
{
    int idx = blockIdx.x * 256 + threadIdx.x;
    int i = idx >> 6, f = idx & 63;
    float nsum = 0.f, dsum = 0.f;
    for (int c = 0; c < chunks; c++) {
        nsum += numP[(size_t)c * (N * FOUT) + idx];
        dsum += denP[(size_t)c * N + i];
    }
    out[idx] = nsum / dsum + bias[f];
}

extern "C" void kernel_launch(void* const* d_in, const int* in_sizes, int n_in,
                              void* d_out, int out_size, void* d_ws, size_t ws_size,
                              hipStream_t stream)
{
    const float* input = (const float*)d_in[0];
    const int*   adj   = (const int*)d_in[1];
    const float* W     = (const float*)d_in[2];
    const float* b_lin = (const float*)d_in[3];
    const float* a     = (const float*)d_in[4];
    const float* bias  = (const float*)d_in[5];
    float* out = (float*)d_out;

    char* ws = (char*)d_ws;
    unsigned short* hTf = (unsigned short*)ws;                   // 1 MiB
    float* s1    = (float*)(ws + 1048576);                       // 32 KB
    float* s2    = (float*)(ws + 1048576 + 32768);               // 32 KB
    unsigned* s2max_enc = (unsigned*)(ws + 1048576 + 65536);     // 4 B (padded to 256)
    size_t fixed = 1048576 + 65536 + 256;

    int log2c = 3;                                               // prefer 8 chunks (XCDs)
    while (log2c > 0) {
        size_t need = (((size_t)N * FOUT + N) * 4u) << log2c;
        if (fixed + need <= ws_size) break;
        log2c--;
    }
    float* numP = (float*)(ws + fixed);
    float* denP = (float*)(ws + fixed + (((size_t)N * FOUT * 4) << log2c));

    hipMemsetAsync(s2max_enc, 0, 4, stream);                     // capture-safe
    hipLaunchKernelGGL(k_linear, dim3(512), dim3(256), 0, stream,
                       input, W, b_lin, a, hTf, s1, s2, s2max_enc);

    int clen = N >> log2c;
    size_t smem = ((size_t)clen << 2) + 256;
    hipLaunchKernelGGL(k_attn, dim3(128 << log2c), dim3(256), smem, stream,
                       adj, s1, s2, hTf, s2max_enc, bias, numP, denP, out, log2c);
    if (log2c > 0)
        hipLaunchKernelGGL(k_finalize, dim3(2048), dim3(256), 0, stream,
                           numP, denP, bias, out, 1 << log2c);
}

// Round 3
// 118.633 us; speedup vs baseline: 1.0896x; 1.0896x over previous
//
#include <hip/hip_runtime.h>

#define N 8192
#define FIN 256
#define FOUT 64
#define ALPHA 0.2f
#define LOG2C 3
#define CLEN (N >> LOG2C)        // 1024 j per chunk

typedef float f32x4 __attribute__((ext_vector_type(4)));
typedef short s16x4 __attribute__((ext_vector_type(4)));

static __device__ __forceinline__ unsigned short f2bf(float x) {
    unsigned u = __float_as_uint(x);
    u += 0x7fffu + ((u >> 16) & 1u);
    return (unsigned short)(u >> 16);
}

// ---------------- Kernel 1: h = input@W + b_lin ---------------------------------------
// Writes hTf (bf16, 16x16 j-major tiles: element (f,j) at [(j>>4)*64+f]*16 + (j&15)),
// s1, s2, and atomicMax's the global s2 max (monotone-uint encoding).
__global__ __launch_bounds__(256) void k_linear(
    const float* __restrict__ input, const float* __restrict__ W,
    const float* __restrict__ b_lin, const float* __restrict__ a,
    unsigned short* __restrict__ hTf, float* __restrict__ s1, float* __restrict__ s2,
    unsigned* __restrict__ s2max_enc)
{
    __shared__ float in_sh[16 * FIN];     // 16 KB
    __shared__ float hst[64][17];         // transpose staging, stride 17 = conflict-free
    int t = threadIdx.x, w = t >> 6, f = t & 63;
    int i0 = blockIdx.x * 16;

#pragma unroll
    for (int r = 0; r < 4; r++) {
        int row = w * 4 + r;
        *(float4*)&in_sh[row * FIN + f * 4] =
            *(const float4*)(input + (size_t)(i0 + row) * FIN + f * 4);
    }

    float a1v = a[f], a2v = a[FOUT + f];
    float h[4];
#pragma unroll
    for (int r = 0; r < 4; r++) h[r] = b_lin[f];

    for (int k4 = 0; k4 < FIN / 4; k4++) {
        float wv0 = W[(k4 * 4 + 0) * FOUT + f];
        float wv1 = W[(k4 * 4 + 1) * FOUT + f];
        float wv2 = W[(k4 * 4 + 2) * FOUT + f];
        float wv3 = W[(k4 * 4 + 3) * FOUT + f];
#pragma unroll
        for (int r = 0; r < 4; r++) {
            float4 iv = *(const float4*)&in_sh[(w * 4 + r) * FIN + k4 * 4];
            h[r] = fmaf(iv.x, wv0, h[r]);
            h[r] = fmaf(iv.y, wv1, h[r]);
            h[r] = fmaf(iv.z, wv2, h[r]);
            h[r] = fmaf(iv.w, wv3, h[r]);
        }
    }

    float wmax = -1e30f;
#pragma unroll
    for (int r = 0; r < 4; r++) {
        hst[f][w * 4 + r] = h[r];
        float v1 = h[r] * a1v, v2 = h[r] * a2v;
#pragma unroll
        for (int d = 1; d < 64; d <<= 1) { v1 += __shfl_xor(v1, d); v2 += __shfl_xor(v2, d); }
        wmax = fmaxf(wmax, v2);
        if (f == 0) { s1[i0 + w * 4 + r] = v1; s2[i0 + w * 4 + r] = v2; }
    }
    if (f == 0) {
        unsigned u = __float_as_uint(wmax);
        unsigned key = (u & 0x80000000u) ? ~u : (u | 0x80000000u);
        atomicMax(s2max_enc, key);
    }
    __syncthreads();

    int fo = t >> 2, seg = t & 3;
    unsigned lo = f2bf(hst[fo][seg * 4 + 0]) | ((unsigned)f2bf(hst[fo][seg * 4 + 1]) << 16);
    unsigned hi = f2bf(hst[fo][seg * 4 + 2]) | ((unsigned)f2bf(hst[fo][seg * 4 + 3]) << 16);
    int2 v; v.x = (int)lo; v.y = (int)hi;
    *(int2*)(hTf + ((size_t)blockIdx.x * 64 + fo) * 16 + seg * 4) = v;
}

// ---------------- Kernel 2: fused mask + exp + P@H via MFMA ---------------------------
// 256 blocks x 512 threads (8 waves = 2/SIMD). chunk = bid&7 = XCD id; rowgroup = bid>>3
// owns 256 rows (2 passes x 8 waves x 16 rows). The chunk's full hT slice (128 KB) + s2
// slice (4 KB) are staged in LDS ONCE -> exactly one barrier in the whole kernel; the
// main loop is barrier-free with 2-iteration-deep adj prefetch (8 KB/wave in flight).
__global__ __launch_bounds__(512) void k_attn(
    const int* __restrict__ adj, const float* __restrict__ s1g,
    const float* __restrict__ s2g, const unsigned short* __restrict__ hTf,
    const unsigned* __restrict__ s2max_enc,
    float* __restrict__ numP, float* __restrict__ denP)
{
    extern __shared__ char smem[];
    unsigned short* hsh = (unsigned short*)smem;            // 64 x 1024 bf16 = 128 KB
    float* s2sh = (float*)(smem + 64 * CLEN * 2);           // 4 KB

    const float LOG2E = 1.4426950408889634f;
    int bid = blockIdx.x;
    int chunk = bid & 7;
    int rg = bid >> 3;                                      // 0..31
    int jstart = chunk * CLEN;
    int t = threadIdx.x, w = t >> 6, l = t & 63;
    int l15 = l & 15, kg = l >> 4;

    // ---- stage hT slice (contiguous 128 KB in global hTf) + s2 slice, one barrier ----
    {
        const int4* src = (const int4*)(hTf + (size_t)jstart * 64);
        int4* dst = (int4*)hsh;
        for (int k = t; k < (64 * CLEN * 2) / 16; k += 512) dst[k] = src[k];
        const float4* s2src = (const float4*)(s2g + jstart);
        for (int k = t; k < CLEN / 4; k += 512) ((float4*)s2sh)[k] = s2src[k];
    }
    unsigned key = *s2max_enc;
    unsigned su = (key & 0x80000000u) ? (key ^ 0x80000000u) : ~key;
    float s2m = __uint_as_float(su);
    __syncthreads();

#pragma unroll
    for (int pass = 0; pass < 2; pass++) {
        int i0 = rg * 256 + pass * 128;
        int i = i0 + w * 16 + l15;                          // this lane's P-row
        float s1v = s1g[i];
        float mx = s1v + s2m; mx = fmaxf(mx, ALPHA * mx);   // leaky(s1+s2max) >= rowmax
        float m2 = mx * LOG2E;

        const int4* adjrow = (const int4*)(adj + (size_t)i * N) + (jstart >> 2);
        int4 a0[4], a1[4];
#pragma unroll
        for (int kb = 0; kb < 4; kb++) a0[kb] = adjrow[kb * 4 + kg];
#pragma unroll
        for (int kb = 0; kb < 4; kb++) a1[kb] = adjrow[16 + kb * 4 + kg];

        f32x4 acc[4] = {};
        float dacc = 0.f;

        for (int it = 0; it < CLEN / 64; it++) {
            int4 anext[4];
            if (it + 2 < CLEN / 64) {
#pragma unroll
                for (int kb = 0; kb < 4; kb++)
                    anext[kb] = adjrow[(it + 2) * 16 + kb * 4 + kg];
            }
            // A fragments (P) in mfma_16x16x16 A layout: row=l15, k=kg*4+e
            s16x4 afr[4];
#pragma unroll
            for (int kb = 0; kb < 4; kb++) {
                float4 sv = *(const float4*)&s2sh[it * 64 + kb * 16 + kg * 4];
                int4 av = a0[kb];
                float p0, p1, p2, p3;
                { float x = s1v + sv.x; x = fmaxf(x, ALPHA * x); p0 = (av.x > 0) ? exp2f(fmaf(x, LOG2E, -m2)) : 0.f; }
                { float x = s1v + sv.y; x = fmaxf(x, ALPHA * x); p1 = (av.y > 0) ? exp2f(fmaf(x, LOG2E, -m2)) : 0.f; }
                { float x = s1v + sv.z; x = fmaxf(x, ALPHA * x); p2 = (av.z > 0) ? exp2f(fmaf(x, LOG2E, -m2)) : 0.f; }
                { float x = s1v + sv.w; x = fmaxf(x, ALPHA * x); p3 = (av.w > 0) ? exp2f(fmaf(x, LOG2E, -m2)) : 0.f; }
                dacc += (p0 + p1) + (p2 + p3);
                s16x4 af;
                af[0] = (short)f2bf(p0); af[1] = (short)f2bf(p1);
                af[2] = (short)f2bf(p2); af[3] = (short)f2bf(p3);
                afr[kb] = af;
            }
            // B fragments from LDS: tile (it*4+kb), dense 512 B per wave read
#pragma unroll
            for (int nt = 0; nt < 4; nt++) {
                const unsigned short* bq = hsh + (size_t)it * 4096 + (nt * 16 + l15) * 16 + kg * 4;
                s16x4 b0 = *(const s16x4*)(bq);
                s16x4 b1 = *(const s16x4*)(bq + 1024);
                s16x4 b2 = *(const s16x4*)(bq + 2048);
                s16x4 b3 = *(const s16x4*)(bq + 3072);
                acc[nt] = __builtin_amdgcn_mfma_f32_16x16x16bf16_1k(afr[0], b0, acc[nt], 0, 0, 0);
                acc[nt] = __builtin_amdgcn_mfma_f32_16x16x16bf16_1k(afr[1], b1, acc[nt], 0, 0, 0);
                acc[nt] = __builtin_amdgcn_mfma_f32_16x16x16bf16_1k(afr[2], b2, acc[nt], 0, 0, 0);
                acc[nt] = __builtin_amdgcn_mfma_f32_16x16x16bf16_1k(afr[3], b3, acc[nt], 0, 0, 0);
            }
#pragma unroll
            for (int kb = 0; kb < 4; kb++) { a0[kb] = a1[kb]; a1[kb] = anext[kb]; }
        }

        dacc += __shfl_xor(dacc, 16);
        dacc += __shfl_xor(dacc, 32);
        if (l < 16) denP[(size_t)chunk * N + i0 + w * 16 + l] = dacc;
#pragma unroll
        for (int nt = 0; nt < 4; nt++) {
#pragma unroll
            for (int r = 0; r < 4; r++) {
                int orow = w * 16 + kg * 4 + r;   // C layout: row=(l>>4)*4+r, col=l&15
                numP[((size_t)chunk * N + i0 + orow) * FOUT + nt * 16 + l15] = acc[nt][r];
            }
        }
    }
}

// ---------------- Kernel 3: combine chunk partials, divide, add bias ------------------
__global__ __launch_bounds__(256) void k_finalize(
    const float* __restrict__ numP, const float* __restrict__ denP,
    const float* __restrict__ bias, float* __restrict__ out)
{
    int idx = blockIdx.x * 256 + threadIdx.x;
    int i = idx >> 6, f = idx & 63;
    float nsum = 0.f, dsum = 0.f;
#pragma unroll
    for (int c = 0; c < 8; c++) {
        nsum += numP[(size_t)c * (N * FOUT) + idx];
        dsum += denP[(size_t)c * N + i];
    }
    out[idx] = nsum / dsum + bias[f];
}

extern "C" void kernel_launch(void* const* d_in, const int* in_sizes, int n_in,
                              void* d_out, int out_size, void* d_ws, size_t ws_size,
                              hipStream_t stream)
{
    const float* input = (const float*)d_in[0];
    const int*   adj   = (const int*)d_in[1];
    const float* W     = (const float*)d_in[2];
    const float* b_lin = (const float*)d_in[3];
    const float* a     = (const float*)d_in[4];
    const float* bias  = (const float*)d_in[5];
    float* out = (float*)d_out;

    char* ws = (char*)d_ws;
    unsigned short* hTf = (unsigned short*)ws;                   // 1 MiB
    float* s1    = (float*)(ws + 1048576);                       // 32 KB
    float* s2    = (float*)(ws + 1048576 + 32768);               // 32 KB
    unsigned* s2max_enc = (unsigned*)(ws + 1048576 + 65536);     // 4 B (padded to 256)
    size_t fixed = 1048576 + 65536 + 256;
    float* numP = (float*)(ws + fixed);                          // 8 x 2 MiB
    float* denP = (float*)(ws + fixed + ((size_t)N * FOUT * 4) * 8);

    size_t smem = (size_t)64 * CLEN * 2 + CLEN * 4;              // 132 KB
    hipFuncSetAttribute((const void*)k_attn,
                        hipFuncAttributeMaxDynamicSharedMemorySize, (int)smem);

    hipMemsetAsync(s2max_enc, 0, 4, stream);                     // capture-safe
    hipLaunchKernelGGL(k_linear, dim3(512), dim3(256), 0, stream,
                       input, W, b_lin, a, hTf, s1, s2, s2max_enc);
    hipLaunchKernelGGL(k_attn, dim3(256), dim3(512), smem, stream,
                       adj, s1, s2, hTf, s2max_enc, numP, denP);
    hipLaunchKernelGGL(k_finalize, dim3(2048), dim3(256), 0, stream,
                       numP, denP, bias, out);
}